// Round 1
// baseline (2427.399 us; speedup 1.0000x reference)
//
#include <hip/hip_runtime.h>
#include <hip/hip_bf16.h>
#include <math.h>

#define TT 512
#define CC 768
#define HH 12
#define DD 64
#define KKEEP 64
#define TOPG 128

// ---------------- helpers ----------------
__device__ __forceinline__ float block_sum(float v, float* red) {
#pragma unroll
  for (int off = 32; off; off >>= 1) v += __shfl_xor(v, off);
  __syncthreads();
  if ((threadIdx.x & 63) == 0) red[threadIdx.x >> 6] = v;
  __syncthreads();
  return red[0] + red[1] + red[2] + red[3];
}

__device__ __forceinline__ float block_max(float v, float* red) {
#pragma unroll
  for (int off = 32; off; off >>= 1) v = fmaxf(v, __shfl_xor(v, off));
  __syncthreads();
  if ((threadIdx.x & 63) == 0) red[threadIdx.x >> 6] = v;
  __syncthreads();
  return fmaxf(fmaxf(red[0], red[1]), fmaxf(red[2], red[3]));
}

// ---------------- layernorm ----------------
__global__ void ln_kernel(const float* __restrict__ x, const float* __restrict__ w,
                          const float* __restrict__ b, float* __restrict__ out) {
  int t = blockIdx.x, tid = threadIdx.x;
  __shared__ float red[4];
  float ls = 0.f;
  for (int c = tid; c < CC; c += 256) ls += x[t * CC + c];
  float mean = block_sum(ls, red) * (1.f / CC);
  float lv = 0.f;
  for (int c = tid; c < CC; c += 256) { float d = x[t * CC + c] - mean; lv += d * d; }
  float var = block_sum(lv, red) * (1.f / CC);
  float rs = rsqrtf(var + 1e-5f);
  for (int c = tid; c < CC; c += 256)
    out[t * CC + c] = (x[t * CC + c] - mean) * rs * w[c] + b[c];
}

// ---------------- generic fp32 GEMM: C = A(MxK) @ W(KxN) (+bias) (+gelu) ----------------
// all of M,N,K are multiples of 32 at our call sites
__global__ void gemm_kernel(const float* __restrict__ A, const float* __restrict__ W,
                            const float* __restrict__ bias, float* __restrict__ C,
                            int M, int N, int K, int act) {
  __shared__ float As[32][33];
  __shared__ float Bs[32][33];
  int tid = threadIdx.x;
  int tx = tid & 15, ty = tid >> 4;
  int n0 = blockIdx.x * 32, m0 = blockIdx.y * 32;
  float acc00 = 0.f, acc01 = 0.f, acc10 = 0.f, acc11 = 0.f;
  for (int k0 = 0; k0 < K; k0 += 32) {
    for (int i = tid; i < 32 * 32; i += 256) {
      int r = i >> 5, c = i & 31;
      As[r][c] = A[(m0 + r) * K + k0 + c];
      Bs[r][c] = W[(k0 + r) * N + n0 + c];
    }
    __syncthreads();
#pragma unroll
    for (int kk = 0; kk < 32; ++kk) {
      float a0 = As[ty * 2][kk], a1 = As[ty * 2 + 1][kk];
      float b0 = Bs[kk][tx * 2], b1 = Bs[kk][tx * 2 + 1];
      acc00 += a0 * b0; acc01 += a0 * b1; acc10 += a1 * b0; acc11 += a1 * b1;
    }
    __syncthreads();
  }
  float accs[2][2] = {{acc00, acc01}, {acc10, acc11}};
#pragma unroll
  for (int i = 0; i < 2; i++)
#pragma unroll
    for (int j = 0; j < 2; j++) {
      int m = m0 + ty * 2 + i, n = n0 + tx * 2 + j;
      float v = accs[i][j] + (bias ? bias[n] : 0.f);
      if (act == 1) v = 0.5f * v * (1.f + erff(v * 0.70710678118654752f));
      C[m * N + n] = v;
    }
}

// ---------------- causal SDPA (per (h,t) block) ----------------
__global__ void sdpa_kernel(const float* __restrict__ qkv, float* __restrict__ y) {
  int h = blockIdx.x, t = blockIdx.y, tid = threadIdx.x;
  __shared__ float qv[DD];
  __shared__ float sc[TT];
  __shared__ float red[4];
  __shared__ float acc2[4][DD];
  if (tid < DD) qv[tid] = qkv[t * 3 * CC + h * DD + tid];
  __syncthreads();
  float lmax = -INFINITY;
  for (int s = tid; s <= t; s += 256) {
    const float* Kp = qkv + s * 3 * CC + CC + h * DD;
    float d = 0.f;
#pragma unroll
    for (int i = 0; i < DD; i++) d += qv[i] * Kp[i];
    d *= 0.125f;
    sc[s] = d;
    lmax = fmaxf(lmax, d);
  }
  float mx = block_max(lmax, red);
  float lsum = 0.f;
  for (int s = tid; s <= t; s += 256) { float e = expf(sc[s] - mx); sc[s] = e; lsum += e; }
  float sum = block_sum(lsum, red);
  __syncthreads();
  int d = tid & 63, c = tid >> 6;
  float part = 0.f;
  for (int s = c; s <= t; s += 4) part += sc[s] * qkv[s * 3 * CC + 2 * CC + h * DD + d];
  acc2[c][d] = part;
  __syncthreads();
  if (tid < DD) {
    float tot = acc2[0][tid] + acc2[1][tid] + acc2[2][tid] + acc2[3][tid];
    y[t * CC + h * DD + tid] = tot / sum;
  }
}

// ---------------- HOA branch logits + top-64 indices (per (h,t) block) ----------------
__global__ void topk_kernel(const float* __restrict__ qh, const float* __restrict__ Kb,
                            int* __restrict__ idxout) {
  int h = blockIdx.x, t = blockIdx.y, tid = threadIdx.x;
  __shared__ float qv[DD];
  __shared__ float sc[TT];
  __shared__ float rv[4];
  __shared__ int ri[4];
  if (tid < DD) qv[tid] = qh[t * CC + h * DD + tid];
  for (int s = tid; s < TT; s += 256) sc[s] = -INFINITY;
  __syncthreads();
  for (int s = tid; s <= t; s += 256) {
    const float* Kp = Kb + s * CC + h * DD;
    float d = 0.f;
#pragma unroll
    for (int i = 0; i < DD; i++) d += qv[i] * Kp[i];
    sc[s] = d * 0.125f;
  }
  __syncthreads();
  int nsel = min(KKEEP, t + 1);
  int* myIdx = idxout + (h * TT + t) * KKEEP;
  for (int j = 0; j < nsel; j++) {
    float bv = -INFINITY; int bi = 0x7fffffff;
    for (int s = tid; s < TT; s += 256) {
      float v = sc[s];
      if (v > bv || (v == bv && s < bi)) { bv = v; bi = s; }
    }
#pragma unroll
    for (int off = 32; off; off >>= 1) {
      float ov = __shfl_xor(bv, off); int oi = __shfl_xor(bi, off);
      if (ov > bv || (ov == bv && oi < bi)) { bv = ov; bi = oi; }
    }
    if ((tid & 63) == 0) { rv[tid >> 6] = bv; ri[tid >> 6] = bi; }
    __syncthreads();
    if (tid == 0) {
      float fv = rv[0]; int fi = ri[0];
      for (int w = 1; w < 4; w++)
        if (rv[w] > fv || (rv[w] == fv && ri[w] < fi)) { fv = rv[w]; fi = ri[w]; }
      myIdx[j] = fi;
      sc[fi] = -INFINITY;
    }
    __syncthreads();
  }
  if (tid == 0) {
    int last = myIdx[nsel - 1];
    for (int j = nsel; j < KKEEP; j++) myIdx[j] = last;
  }
}

// ---------------- HOA core (per (h,t) block) ----------------
__global__ void hoa_core_kernel(const float* __restrict__ qh,
                                const float* __restrict__ K1, const float* __restrict__ K2,
                                const float* __restrict__ V1, const float* __restrict__ V2,
                                const int* __restrict__ idx1, const int* __restrict__ idx2,
                                float* __restrict__ hco) {
  int h = blockIdx.x, t = blockIdx.y, tid = threadIdx.x;
  __shared__ float g1[KKEEP][DD + 1];
  __shared__ float g2[KKEEP][DD + 1];
  __shared__ float A[KKEEP][KKEEP + 1];
  __shared__ float qv[DD];
  if (tid < DD) qv[tid] = qh[t * CC + h * DD + tid];
  __syncthreads();
  const int* i1 = idx1 + (h * TT + t) * KKEEP;
  const int* i2 = idx2 + (h * TT + t) * KKEEP;
  for (int e = tid; e < KKEEP * DD; e += 256) {
    int j = e >> 6, d = e & 63;
    g1[j][d] = K1[i1[j] * CC + h * DD + d] * qv[d];
    g2[j][d] = K2[i2[j] * CC + h * DD + d];
  }
  __syncthreads();
  for (int e = tid; e < KKEEP * KKEEP; e += 256) {
    int j = e >> 6, k = e & 63;
    float s = 0.f;
#pragma unroll
    for (int d = 0; d < DD; d++) s += g1[j][d] * g2[k][d];
    A[j][k] = s * 0.125f;
  }
  __syncthreads();
  // row softmax over k (4 threads per row)
  {
    int j = tid >> 2, p = tid & 3;
    float m = -INFINITY;
    for (int k = p; k < KKEEP; k += 4) m = fmaxf(m, A[j][k]);
#pragma unroll
    for (int off = 1; off < 4; off <<= 1) m = fmaxf(m, __shfl_xor(m, off));
    float s = 0.f;
    float ex[16];
#pragma unroll
    for (int c = 0; c < 16; c++) {
      int k = p + 4 * c;
      float e = expf(A[j][k] - m);
      ex[c] = e; s += e;
    }
#pragma unroll
    for (int off = 1; off < 4; off <<= 1) s += __shfl_xor(s, off);
    float inv = 1.f / s;
#pragma unroll
    for (int c = 0; c < 16; c++) A[j][p + 4 * c] = ex[c] * inv;
  }
  __syncthreads();
  // gather V into g1,g2
  for (int e = tid; e < KKEEP * DD; e += 256) {
    int j = e >> 6, d = e & 63;
    g1[j][d] = V1[i1[j] * CC + h * DD + d];
    g2[j][d] = V2[i2[j] * CC + h * DD + d];
  }
  __syncthreads();
  // out[d] = sum_j g1[j][d] * (sum_k alpha[j][k] * g2[k][d])
  int d = tid >> 2, p = tid & 3;
  float acc = 0.f;
  for (int j = p; j < KKEEP; j += 4) {
    float m = 0.f;
#pragma unroll
    for (int k = 0; k < KKEEP; k++) m += A[j][k] * g2[k][d];
    acc += g1[j][d] * m;
  }
#pragma unroll
  for (int off = 1; off < 4; off <<= 1) acc += __shfl_xor(acc, off);
  if (p == 0) hco[t * CC + h * DD + d] = acc;
}

// ---------------- gate ----------------
__global__ void gate_scores_kernel(const float* __restrict__ hoin,
                                   const float* __restrict__ gw, const float* __restrict__ gb,
                                   float* __restrict__ scores) {
  int t = blockIdx.x, tid = threadIdx.x;
  __shared__ float red[4];
  float part = 0.f;
  for (int c = tid; c < CC; c += 256) part += hoin[t * CC + c] * gw[c];
  float s = block_sum(part, red);
  if (tid == 0) scores[t] = s + gb[0];
}

__global__ void gate_mask_kernel(const float* __restrict__ scores, float* __restrict__ mask) {
  int tid = threadIdx.x;
  __shared__ float sc[TT];
  __shared__ float rv[4];
  __shared__ int ri[4];
  for (int s = tid; s < TT; s += 256) { sc[s] = scores[s]; mask[s] = 0.f; }
  __syncthreads();
  for (int j = 0; j < TOPG; j++) {
    float bv = -INFINITY; int bi = 0x7fffffff;
    for (int s = tid; s < TT; s += 256) {
      float v = sc[s];
      if (v > bv || (v == bv && s < bi)) { bv = v; bi = s; }
    }
#pragma unroll
    for (int off = 32; off; off >>= 1) {
      float ov = __shfl_xor(bv, off); int oi = __shfl_xor(bi, off);
      if (ov > bv || (ov == bv && oi < bi)) { bv = ov; bi = oi; }
    }
    if ((tid & 63) == 0) { rv[tid >> 6] = bv; ri[tid >> 6] = bi; }
    __syncthreads();
    if (tid == 0) {
      float fv = rv[0]; int fi = ri[0];
      for (int w = 1; w < 4; w++)
        if (rv[w] > fv || (rv[w] == fv && ri[w] < fi)) { fv = rv[w]; fi = ri[w]; }
      mask[fi] = 1.f;
      sc[fi] = -INFINITY;
    }
    __syncthreads();
  }
}

// ---------------- elementwise ----------------
__global__ void add_kernel(const float* __restrict__ a, const float* __restrict__ b,
                           float* __restrict__ o, int n) {
  int i = blockIdx.x * 256 + threadIdx.x;
  if (i < n) o[i] = a[i] + b[i];
}

__global__ void masked_add_kernel(const float* __restrict__ a, const float* __restrict__ b,
                                  const float* __restrict__ mask, float* __restrict__ o, int n) {
  int i = blockIdx.x * 256 + threadIdx.x;
  if (i < n) o[i] = a[i] + b[i] * mask[i / CC];
}

// ---------------- launcher ----------------
extern "C" void kernel_launch(void* const* d_in, const int* in_sizes, int n_in,
                              void* d_out, int out_size, void* d_ws, size_t ws_size,
                              hipStream_t stream) {
  const float* x      = (const float*)d_in[0];
  const float* ln1_w  = (const float*)d_in[1];
  const float* ln1_b  = (const float*)d_in[2];
  const float* qkv_w  = (const float*)d_in[3];
  const float* qkv_b  = (const float*)d_in[4];
  const float* atto_w = (const float*)d_in[5];
  const float* atto_b = (const float*)d_in[6];
  const float* lnh_w  = (const float*)d_in[7];
  const float* lnh_b  = (const float*)d_in[8];
  const float* hq_w   = (const float*)d_in[9];
  const float* hk1_w  = (const float*)d_in[10];
  const float* hk2_w  = (const float*)d_in[11];
  const float* hv1_w  = (const float*)d_in[12];
  const float* hv2_w  = (const float*)d_in[13];
  const float* ho_w   = (const float*)d_in[14];
  const float* gate_w = (const float*)d_in[15];
  const float* gate_b = (const float*)d_in[16];
  const float* ln2_w  = (const float*)d_in[17];
  const float* ln2_b  = (const float*)d_in[18];
  const float* fc_w   = (const float*)d_in[19];
  const float* fc_b   = (const float*)d_in[20];
  const float* pr_w   = (const float*)d_in[21];
  const float* pr_b   = (const float*)d_in[22];
  float* out = (float*)d_out;

  const size_t NTC = (size_t)TT * CC;  // 393216
  float* ws   = (float*)d_ws;
  float* h    = ws;
  float* qkv  = h + NTC;          // 3*NTC
  float* y    = qkv + 3 * NTC;
  float* x1   = y + NTC;
  float* hoin = x1 + NTC;
  float* qh   = hoin + NTC;
  float* K1   = qh + NTC;
  float* K2   = K1 + NTC;
  float* V1   = K2 + NTC;
  float* V2   = V1 + NTC;
  float* hco  = V2 + NTC;
  float* hout = hco + NTC;
  float* x2   = hout + NTC;
  float* h2   = x2 + NTC;
  float* fcb  = h2 + NTC;         // 4*NTC
  float* scores = fcb + 4 * NTC;  // 512
  float* maskb  = scores + TT;    // 512
  int* idx1 = (int*)(maskb + TT);
  int* idx2 = idx1 + HH * TT * KKEEP;

  dim3 blk(256);
  int nElem = (int)NTC;
  int nBlocks = (nElem + 255) / 256;

  // 1) LN1
  hipLaunchKernelGGL(ln_kernel, dim3(TT), blk, 0, stream, x, ln1_w, ln1_b, h);
  // 2) QKV GEMM
  hipLaunchKernelGGL(gemm_kernel, dim3(3 * CC / 32, TT / 32), blk, 0, stream,
                     h, qkv_w, qkv_b, qkv, TT, 3 * CC, CC, 0);
  // 3) SDPA
  hipLaunchKernelGGL(sdpa_kernel, dim3(HH, TT), blk, 0, stream, qkv, y);
  // 4) out proj + residual
  hipLaunchKernelGGL(gemm_kernel, dim3(CC / 32, TT / 32), blk, 0, stream,
                     y, atto_w, atto_b, h, TT, CC, CC, 0);
  hipLaunchKernelGGL(add_kernel, dim3(nBlocks), blk, 0, stream, x, h, x1, nElem);
  // 5) LN_h
  hipLaunchKernelGGL(ln_kernel, dim3(TT), blk, 0, stream, x1, lnh_w, lnh_b, hoin);
  // 6) HOA projections
  hipLaunchKernelGGL(gemm_kernel, dim3(CC / 32, TT / 32), blk, 0, stream,
                     hoin, hq_w, (const float*)nullptr, qh, TT, CC, CC, 0);
  hipLaunchKernelGGL(gemm_kernel, dim3(CC / 32, TT / 32), blk, 0, stream,
                     hoin, hk1_w, (const float*)nullptr, K1, TT, CC, CC, 0);
  hipLaunchKernelGGL(gemm_kernel, dim3(CC / 32, TT / 32), blk, 0, stream,
                     hoin, hk2_w, (const float*)nullptr, K2, TT, CC, CC, 0);
  hipLaunchKernelGGL(gemm_kernel, dim3(CC / 32, TT / 32), blk, 0, stream,
                     hoin, hv1_w, (const float*)nullptr, V1, TT, CC, CC, 0);
  hipLaunchKernelGGL(gemm_kernel, dim3(CC / 32, TT / 32), blk, 0, stream,
                     hoin, hv2_w, (const float*)nullptr, V2, TT, CC, CC, 0);
  // 7) top-64 per branch
  hipLaunchKernelGGL(topk_kernel, dim3(HH, TT), blk, 0, stream, qh, K1, idx1);
  hipLaunchKernelGGL(topk_kernel, dim3(HH, TT), blk, 0, stream, qh, K2, idx2);
  // 8) HOA core
  hipLaunchKernelGGL(hoa_core_kernel, dim3(HH, TT), blk, 0, stream,
                     qh, K1, K2, V1, V2, idx1, idx2, hco);
  // 9) HOA out proj
  hipLaunchKernelGGL(gemm_kernel, dim3(CC / 32, TT / 32), blk, 0, stream,
                     hco, ho_w, (const float*)nullptr, hout, TT, CC, CC, 0);
  // 10-11) gate
  hipLaunchKernelGGL(gate_scores_kernel, dim3(TT), blk, 0, stream, hoin, gate_w, gate_b, scores);
  hipLaunchKernelGGL(gate_mask_kernel, dim3(1), blk, 0, stream, scores, maskb);
  // 12) masked residual
  hipLaunchKernelGGL(masked_add_kernel, dim3(nBlocks), blk, 0, stream, x1, hout, maskb, x2, nElem);
  // 13) LN2
  hipLaunchKernelGGL(ln_kernel, dim3(TT), blk, 0, stream, x2, ln2_w, ln2_b, h2);
  // 14) MLP fc + gelu
  hipLaunchKernelGGL(gemm_kernel, dim3(4 * CC / 32, TT / 32), blk, 0, stream,
                     h2, fc_w, fc_b, fcb, TT, 4 * CC, CC, 1);
  // 15) MLP proj
  hipLaunchKernelGGL(gemm_kernel, dim3(CC / 32, TT / 32), blk, 0, stream,
                     fcb, pr_w, pr_b, h, TT, CC, 4 * CC, 0);
  // 16) final residual -> out
  hipLaunchKernelGGL(add_kernel, dim3(nBlocks), blk, 0, stream, x2, h, out, nElem);
}

// Round 2
// 1134.548 us; speedup vs baseline: 2.1395x; 2.1395x over previous
//
#include <hip/hip_runtime.h>
#include <hip/hip_bf16.h>
#include <math.h>

#define TT 512
#define CC 768
#define HH 12
#define DD 64
#define KKEEP 64
#define TOPG 128

typedef __attribute__((ext_vector_type(8))) short bf16x8;
typedef __attribute__((ext_vector_type(4))) float f32x4;

// ---------------- helpers ----------------
__device__ __forceinline__ float block_sum(float v, float* red) {
#pragma unroll
  for (int off = 32; off; off >>= 1) v += __shfl_xor(v, off);
  __syncthreads();
  if ((threadIdx.x & 63) == 0) red[threadIdx.x >> 6] = v;
  __syncthreads();
  return red[0] + red[1] + red[2] + red[3];
}

__device__ __forceinline__ float block_max(float v, float* red) {
#pragma unroll
  for (int off = 32; off; off >>= 1) v = fmaxf(v, __shfl_xor(v, off));
  __syncthreads();
  if ((threadIdx.x & 63) == 0) red[threadIdx.x >> 6] = v;
  __syncthreads();
  return fmaxf(fmaxf(red[0], red[1]), fmaxf(red[2], red[3]));
}

__device__ __forceinline__ unsigned short f32_to_bf16_rne(float f) {
  unsigned u = __float_as_uint(f);
  unsigned r = (u + 0x7FFFu + ((u >> 16) & 1u)) >> 16;
  return (unsigned short)r;
}
__device__ __forceinline__ float bf16_to_f32(unsigned short h) {
  return __uint_as_float(((unsigned)h) << 16);
}

// ---------------- layernorm ----------------
__global__ void ln_kernel(const float* __restrict__ x, const float* __restrict__ w,
                          const float* __restrict__ b, float* __restrict__ out) {
  int t = blockIdx.x, tid = threadIdx.x;
  __shared__ float red[4];
  float ls = 0.f;
  for (int c = tid; c < CC; c += 256) ls += x[t * CC + c];
  float mean = block_sum(ls, red) * (1.f / CC);
  float lv = 0.f;
  for (int c = tid; c < CC; c += 256) { float d = x[t * CC + c] - mean; lv += d * d; }
  float var = block_sum(lv, red) * (1.f / CC);
  float rs = rsqrtf(var + 1e-5f);
  for (int c = tid; c < CC; c += 256)
    out[t * CC + c] = (x[t * CC + c] - mean) * rs * w[c] + b[c];
}

// ---------------- split-bf16 MFMA GEMM: C = A(MxK) @ W(KxN) (+bias) (+gelu) ----------------
__global__ __launch_bounds__(256) void gemm_mfma(
    const float* __restrict__ A, const float* __restrict__ W,
    const float* __restrict__ bias, float* __restrict__ C,
    int M, int N, int K, int act) {
  __shared__ unsigned short Ah[64 * 64];
  __shared__ unsigned short Al[64 * 64];
  __shared__ unsigned short Bh[64 * 64];
  __shared__ unsigned short Bl[64 * 64];
  int tid = threadIdx.x;
  int lane = tid & 63, wave = tid >> 6;
  int wr = wave >> 1, wc = wave & 1;
  int lr = lane & 15;
  int ksub = (lane >> 4) * 8;
  int n0 = blockIdx.x * 64, m0 = blockIdx.y * 64;

  f32x4 acc[2][2];
#pragma unroll
  for (int i = 0; i < 2; i++)
#pragma unroll
    for (int j = 0; j < 2; j++) acc[i][j] = (f32x4){0.f, 0.f, 0.f, 0.f};

  int lrow = tid >> 2;
  int lq = tid & 3;

  for (int k0 = 0; k0 < K; k0 += 64) {
    {
      const float* src = A + (size_t)(m0 + lrow) * K + k0 + lq * 16;
#pragma unroll
      for (int f = 0; f < 4; f++) {
        float4 v = *(const float4*)(src + f * 4);
        int kk = lq * 16 + f * 4;
        int g = kk >> 3;
        int off = lrow * 64 + ((g ^ (lrow & 7)) << 3) + (kk & 7);
        unsigned short h0 = f32_to_bf16_rne(v.x), h1 = f32_to_bf16_rne(v.y);
        unsigned short h2 = f32_to_bf16_rne(v.z), h3 = f32_to_bf16_rne(v.w);
        *(ushort4*)&Ah[off] = make_ushort4(h0, h1, h2, h3);
        *(ushort4*)&Al[off] = make_ushort4(
            f32_to_bf16_rne(v.x - bf16_to_f32(h0)), f32_to_bf16_rne(v.y - bf16_to_f32(h1)),
            f32_to_bf16_rne(v.z - bf16_to_f32(h2)), f32_to_bf16_rne(v.w - bf16_to_f32(h3)));
      }
    }
    {
      const float* src = W + (size_t)(k0 + lrow) * N + n0 + lq * 16;
      int g = lrow >> 3, krem = lrow & 7;
#pragma unroll
      for (int f = 0; f < 4; f++) {
        float4 v = *(const float4*)(src + f * 4);
        float vv[4] = {v.x, v.y, v.z, v.w};
#pragma unroll
        for (int e = 0; e < 4; e++) {
          int n = lq * 16 + f * 4 + e;
          int off = n * 64 + ((g ^ (n & 7)) << 3) + krem;
          unsigned short hh = f32_to_bf16_rne(vv[e]);
          Bh[off] = hh;
          Bl[off] = f32_to_bf16_rne(vv[e] - bf16_to_f32(hh));
        }
      }
    }
    __syncthreads();
#pragma unroll
    for (int kb = 0; kb < 2; kb++) {
      int kloc = kb * 32 + ksub;
      int g = kloc >> 3;
      bf16x8 ah[2], al[2], bh[2], bl[2];
#pragma unroll
      for (int i = 0; i < 2; i++) {
        int m = wr * 32 + i * 16 + lr;
        int off = m * 64 + ((g ^ (m & 7)) << 3);
        ah[i] = *(const bf16x8*)&Ah[off];
        al[i] = *(const bf16x8*)&Al[off];
      }
#pragma unroll
      for (int j = 0; j < 2; j++) {
        int n = wc * 32 + j * 16 + lr;
        int off = n * 64 + ((g ^ (n & 7)) << 3);
        bh[j] = *(const bf16x8*)&Bh[off];
        bl[j] = *(const bf16x8*)&Bl[off];
      }
#pragma unroll
      for (int i = 0; i < 2; i++)
#pragma unroll
        for (int j = 0; j < 2; j++) {
          acc[i][j] = __builtin_amdgcn_mfma_f32_16x16x32_bf16(ah[i], bh[j], acc[i][j], 0, 0, 0);
          acc[i][j] = __builtin_amdgcn_mfma_f32_16x16x32_bf16(ah[i], bl[j], acc[i][j], 0, 0, 0);
          acc[i][j] = __builtin_amdgcn_mfma_f32_16x16x32_bf16(al[i], bh[j], acc[i][j], 0, 0, 0);
        }
    }
    __syncthreads();
  }
#pragma unroll
  for (int i = 0; i < 2; i++)
#pragma unroll
    for (int j = 0; j < 2; j++) {
      int col = n0 + wc * 32 + j * 16 + lr;
      float bv = bias ? bias[col] : 0.f;
#pragma unroll
      for (int q = 0; q < 4; q++) {
        int row = m0 + wr * 32 + i * 16 + (lane >> 4) * 4 + q;
        float v = acc[i][j][q] + bv;
        if (act == 1) v = 0.5f * v * (1.f + erff(v * 0.70710678118654752f));
        C[(size_t)row * N + col] = v;
      }
    }
}

// ---------------- causal SDPA ----------------
__global__ void sdpa_kernel(const float* __restrict__ qkv, float* __restrict__ y) {
  int h = blockIdx.x, t = blockIdx.y, tid = threadIdx.x;
  __shared__ float qv[DD];
  __shared__ float sc[TT];
  __shared__ float red[4];
  __shared__ float acc2[4][DD];
  if (tid < DD) qv[tid] = qkv[t * 3 * CC + h * DD + tid];
  __syncthreads();
  float lmax = -INFINITY;
  for (int s = tid; s <= t; s += 256) {
    const float* Kp = qkv + s * 3 * CC + CC + h * DD;
    float d = 0.f;
#pragma unroll
    for (int i = 0; i < DD; i++) d += qv[i] * Kp[i];
    d *= 0.125f;
    sc[s] = d;
    lmax = fmaxf(lmax, d);
  }
  float mx = block_max(lmax, red);
  float lsum = 0.f;
  for (int s = tid; s <= t; s += 256) { float e = expf(sc[s] - mx); sc[s] = e; lsum += e; }
  float sum = block_sum(lsum, red);
  __syncthreads();
  int d = tid & 63, c = tid >> 6;
  float part = 0.f;
  for (int s = c; s <= t; s += 4) part += sc[s] * qkv[s * 3 * CC + 2 * CC + h * DD + d];
  acc2[c][d] = part;
  __syncthreads();
  if (tid < DD) {
    float tot = acc2[0][tid] + acc2[1][tid] + acc2[2][tid] + acc2[3][tid];
    y[t * CC + h * DD + tid] = tot / sum;
  }
}

// ---------------- HOA top-64 via bitonic sort ----------------
__global__ void topk_sort_kernel(const float* __restrict__ qh,
                                 const float* __restrict__ K1, const float* __restrict__ K2,
                                 int* __restrict__ idx1, int* __restrict__ idx2) {
  int h = blockIdx.x, t = blockIdx.y, tid = threadIdx.x;
  const float* Kb = blockIdx.z ? K2 : K1;
  int* idxout = (blockIdx.z ? idx2 : idx1) + (h * TT + t) * KKEEP;
  __shared__ float qv[DD];
  __shared__ unsigned long long keys[TT];
  if (tid < DD) qv[tid] = qh[t * CC + h * DD + tid];
  __syncthreads();
  for (int s = tid; s < TT; s += 256) {
    unsigned sv = 0u;
    if (s <= t) {
      const float* Kp = Kb + s * CC + h * DD;
      float d = 0.f;
#pragma unroll
      for (int i = 0; i < DD; i++) d += qv[i] * Kp[i];
      unsigned u = __float_as_uint(d);
      sv = (u & 0x80000000u) ? ~u : (u | 0x80000000u);
    }
    keys[s] = ((unsigned long long)sv << 32) | (unsigned)(~s);
  }
  for (int k = 2; k <= TT; k <<= 1) {
    for (int j = k >> 1; j > 0; j >>= 1) {
      __syncthreads();
      for (int i = tid; i < TT; i += 256) {
        int ixj = i ^ j;
        if (ixj > i) {
          unsigned long long a = keys[i], b = keys[ixj];
          bool desc = (i & k) == 0;
          if (desc ? (a < b) : (a > b)) { keys[i] = b; keys[ixj] = a; }
        }
      }
    }
  }
  __syncthreads();
  for (int jj = tid; jj < KKEEP; jj += 256) {
    unsigned long long key = keys[jj <= t ? jj : t];
    idxout[jj] = (int)(~(unsigned)key);
  }
}

// ---------------- HOA core ----------------
__global__ void hoa_core_kernel(const float* __restrict__ qh,
                                const float* __restrict__ K1, const float* __restrict__ K2,
                                const float* __restrict__ V1, const float* __restrict__ V2,
                                const int* __restrict__ idx1, const int* __restrict__ idx2,
                                float* __restrict__ hco) {
  int h = blockIdx.x, t = blockIdx.y, tid = threadIdx.x;
  __shared__ float g1[KKEEP][DD + 1];
  __shared__ float g2[KKEEP][DD + 1];
  __shared__ float A[KKEEP][KKEEP + 1];
  __shared__ float qv[DD];
  if (tid < DD) qv[tid] = qh[t * CC + h * DD + tid];
  __syncthreads();
  const int* i1 = idx1 + (h * TT + t) * KKEEP;
  const int* i2 = idx2 + (h * TT + t) * KKEEP;
  for (int e = tid; e < KKEEP * DD; e += 256) {
    int j = e >> 6, d = e & 63;
    g1[j][d] = K1[i1[j] * CC + h * DD + d] * qv[d];
    g2[j][d] = K2[i2[j] * CC + h * DD + d];
  }
  __syncthreads();
  for (int e = tid; e < KKEEP * KKEEP; e += 256) {
    int j = e >> 6, k = e & 63;
    float s = 0.f;
#pragma unroll
    for (int d = 0; d < DD; d++) s += g1[j][d] * g2[k][d];
    A[j][k] = s * 0.125f;
  }
  __syncthreads();
  {
    int j = tid >> 2, p = tid & 3;
    float m = -INFINITY;
    for (int k = p; k < KKEEP; k += 4) m = fmaxf(m, A[j][k]);
#pragma unroll
    for (int off = 1; off < 4; off <<= 1) m = fmaxf(m, __shfl_xor(m, off));
    float s = 0.f;
    float ex[16];
#pragma unroll
    for (int c = 0; c < 16; c++) {
      int k = p + 4 * c;
      float e = expf(A[j][k] - m);
      ex[c] = e; s += e;
    }
#pragma unroll
    for (int off = 1; off < 4; off <<= 1) s += __shfl_xor(s, off);
    float inv = 1.f / s;
#pragma unroll
    for (int c = 0; c < 16; c++) A[j][p + 4 * c] = ex[c] * inv;
  }
  __syncthreads();
  for (int e = tid; e < KKEEP * DD; e += 256) {
    int j = e >> 6, d = e & 63;
    g1[j][d] = V1[i1[j] * CC + h * DD + d];
    g2[j][d] = V2[i2[j] * CC + h * DD + d];
  }
  __syncthreads();
  int d = tid >> 2, p = tid & 3;
  float acc = 0.f;
  for (int j = p; j < KKEEP; j += 4) {
    float m = 0.f;
#pragma unroll
    for (int k = 0; k < KKEEP; k++) m += A[j][k] * g2[k][d];
    acc += g1[j][d] * m;
  }
#pragma unroll
  for (int off = 1; off < 4; off <<= 1) acc += __shfl_xor(acc, off);
  if (p == 0) hco[t * CC + h * DD + d] = acc;
}

// ---------------- gate ----------------
__global__ void gate_scores_kernel(const float* __restrict__ hoin,
                                   const float* __restrict__ gw, const float* __restrict__ gb,
                                   float* __restrict__ scores) {
  int t = blockIdx.x, tid = threadIdx.x;
  __shared__ float red[4];
  float part = 0.f;
  for (int c = tid; c < CC; c += 256) part += hoin[t * CC + c] * gw[c];
  float s = block_sum(part, red);
  if (tid == 0) scores[t] = s + gb[0];
}

__global__ void gate_mask_kernel(const float* __restrict__ scores, float* __restrict__ mask) {
  int tid = threadIdx.x;
  __shared__ unsigned long long keys[TT];
  for (int s = tid; s < TT; s += 256) {
    unsigned u = __float_as_uint(scores[s]);
    unsigned sv = (u & 0x80000000u) ? ~u : (u | 0x80000000u);
    keys[s] = ((unsigned long long)sv << 32) | (unsigned)(~s);
    mask[s] = 0.f;
  }
  for (int k = 2; k <= TT; k <<= 1) {
    for (int j = k >> 1; j > 0; j >>= 1) {
      __syncthreads();
      for (int i = tid; i < TT; i += 256) {
        int ixj = i ^ j;
        if (ixj > i) {
          unsigned long long a = keys[i], b = keys[ixj];
          bool desc = (i & k) == 0;
          if (desc ? (a < b) : (a > b)) { keys[i] = b; keys[ixj] = a; }
        }
      }
    }
  }
  __syncthreads();
  for (int jj = tid; jj < TOPG; jj += 256) mask[(int)(~(unsigned)keys[jj])] = 1.f;
}

// ---------------- elementwise ----------------
__global__ void add_kernel(const float* __restrict__ a, const float* __restrict__ b,
                           float* __restrict__ o, int n) {
  int i = blockIdx.x * 256 + threadIdx.x;
  if (i < n) o[i] = a[i] + b[i];
}

__global__ void masked_add_kernel(const float* __restrict__ a, const float* __restrict__ b,
                                  const float* __restrict__ mask, float* __restrict__ o, int n) {
  int i = blockIdx.x * 256 + threadIdx.x;
  if (i < n) o[i] = a[i] + b[i] * mask[i / CC];
}

// ---------------- launcher ----------------
extern "C" void kernel_launch(void* const* d_in, const int* in_sizes, int n_in,
                              void* d_out, int out_size, void* d_ws, size_t ws_size,
                              hipStream_t stream) {
  const float* x      = (const float*)d_in[0];
  const float* ln1_w  = (const float*)d_in[1];
  const float* ln1_b  = (const float*)d_in[2];
  const float* qkv_w  = (const float*)d_in[3];
  const float* qkv_b  = (const float*)d_in[4];
  const float* atto_w = (const float*)d_in[5];
  const float* atto_b = (const float*)d_in[6];
  const float* lnh_w  = (const float*)d_in[7];
  const float* lnh_b  = (const float*)d_in[8];
  const float* hq_w   = (const float*)d_in[9];
  const float* hk1_w  = (const float*)d_in[10];
  const float* hk2_w  = (const float*)d_in[11];
  const float* hv1_w  = (const float*)d_in[12];
  const float* hv2_w  = (const float*)d_in[13];
  const float* ho_w   = (const float*)d_in[14];
  const float* gate_w = (const float*)d_in[15];
  const float* gate_b = (const float*)d_in[16];
  const float* ln2_w  = (const float*)d_in[17];
  const float* ln2_b  = (const float*)d_in[18];
  const float* fc_w   = (const float*)d_in[19];
  const float* fc_b   = (const float*)d_in[20];
  const float* pr_w   = (const float*)d_in[21];
  const float* pr_b   = (const float*)d_in[22];
  float* out = (float*)d_out;

  const size_t NTC = (size_t)TT * CC;
  float* ws   = (float*)d_ws;
  float* h    = ws;
  float* qkv  = h + NTC;
  float* y    = qkv + 3 * NTC;
  float* x1   = y + NTC;
  float* hoin = x1 + NTC;
  float* qh   = hoin + NTC;
  float* K1   = qh + NTC;
  float* K2   = K1 + NTC;
  float* V1   = K2 + NTC;
  float* V2   = V1 + NTC;
  float* hco  = V2 + NTC;
  float* hout = hco + NTC;
  float* x2   = hout + NTC;
  float* h2   = x2 + NTC;
  float* fcb  = h2 + NTC;
  float* scores = fcb + 4 * NTC;
  float* maskb  = scores + TT;
  int* idx1 = (int*)(maskb + TT);
  int* idx2 = idx1 + HH * TT * KKEEP;

  dim3 blk(256);
  int nElem = (int)NTC;
  int nBlocks = (nElem + 255) / 256;

  hipLaunchKernelGGL(ln_kernel, dim3(TT), blk, 0, stream, x, ln1_w, ln1_b, h);
  hipLaunchKernelGGL(gemm_mfma, dim3(3 * CC / 64, TT / 64), blk, 0, stream,
                     h, qkv_w, qkv_b, qkv, TT, 3 * CC, CC, 0);
  hipLaunchKernelGGL(sdpa_kernel, dim3(HH, TT), blk, 0, stream, qkv, y);
  hipLaunchKernelGGL(gemm_mfma, dim3(CC / 64, TT / 64), blk, 0, stream,
                     y, atto_w, atto_b, h, TT, CC, CC, 0);
  hipLaunchKernelGGL(add_kernel, dim3(nBlocks), blk, 0, stream, x, h, x1, nElem);
  hipLaunchKernelGGL(ln_kernel, dim3(TT), blk, 0, stream, x1, lnh_w, lnh_b, hoin);
  hipLaunchKernelGGL(gemm_mfma, dim3(CC / 64, TT / 64), blk, 0, stream,
                     hoin, hq_w, (const float*)nullptr, qh, TT, CC, CC, 0);
  hipLaunchKernelGGL(gemm_mfma, dim3(CC / 64, TT / 64), blk, 0, stream,
                     hoin, hk1_w, (const float*)nullptr, K1, TT, CC, CC, 0);
  hipLaunchKernelGGL(gemm_mfma, dim3(CC / 64, TT / 64), blk, 0, stream,
                     hoin, hk2_w, (const float*)nullptr, K2, TT, CC, CC, 0);
  hipLaunchKernelGGL(gemm_mfma, dim3(CC / 64, TT / 64), blk, 0, stream,
                     hoin, hv1_w, (const float*)nullptr, V1, TT, CC, CC, 0);
  hipLaunchKernelGGL(gemm_mfma, dim3(CC / 64, TT / 64), blk, 0, stream,
                     hoin, hv2_w, (const float*)nullptr, V2, TT, CC, CC, 0);
  hipLaunchKernelGGL(topk_sort_kernel, dim3(HH, TT, 2), blk, 0, stream,
                     qh, K1, K2, idx1, idx2);
  hipLaunchKernelGGL(hoa_core_kernel, dim3(HH, TT), blk, 0, stream,
                     qh, K1, K2, V1, V2, idx1, idx2, hco);
  hipLaunchKernelGGL(gemm_mfma, dim3(CC / 64, TT / 64), blk, 0, stream,
                     hco, ho_w, (const float*)nullptr, hout, TT, CC, CC, 0);
  hipLaunchKernelGGL(gate_scores_kernel, dim3(TT), blk, 0, stream, hoin, gate_w, gate_b, scores);
  hipLaunchKernelGGL(gate_mask_kernel, dim3(1), blk, 0, stream, scores, maskb);
  hipLaunchKernelGGL(masked_add_kernel, dim3(nBlocks), blk, 0, stream, x1, hout, maskb, x2, nElem);
  hipLaunchKernelGGL(ln_kernel, dim3(TT), blk, 0, stream, x2, ln2_w, ln2_b, h2);
  hipLaunchKernelGGL(gemm_mfma, dim3(4 * CC / 64, TT / 64), blk, 0, stream,
                     h2, fc_w, fc_b, fcb, TT, 4 * CC, CC, 1);
  hipLaunchKernelGGL(gemm_mfma, dim3(CC / 64, TT / 64), blk, 0, stream,
                     fcb, pr_w, pr_b, h, TT, CC, 4 * CC, 0);
  hipLaunchKernelGGL(add_kernel, dim3(nBlocks), blk, 0, stream, x2, h, out, nElem);
}

// Round 3
// 698.735 us; speedup vs baseline: 3.4740x; 1.6237x over previous
//
#include <hip/hip_runtime.h>
#include <hip/hip_bf16.h>
#include <math.h>

#define TT 512
#define CC 768
#define HH 12
#define DD 64
#define KKEEP 64
#define TOPG 128

typedef __attribute__((ext_vector_type(8))) short bf16x8;
typedef __attribute__((ext_vector_type(4))) float f32x4;

// ---------------- helpers ----------------
__device__ __forceinline__ float block_sum(float v, float* red) {
#pragma unroll
  for (int off = 32; off; off >>= 1) v += __shfl_xor(v, off);
  __syncthreads();
  if ((threadIdx.x & 63) == 0) red[threadIdx.x >> 6] = v;
  __syncthreads();
  return red[0] + red[1] + red[2] + red[3];
}

__device__ __forceinline__ float block_max(float v, float* red) {
#pragma unroll
  for (int off = 32; off; off >>= 1) v = fmaxf(v, __shfl_xor(v, off));
  __syncthreads();
  if ((threadIdx.x & 63) == 0) red[threadIdx.x >> 6] = v;
  __syncthreads();
  return fmaxf(fmaxf(red[0], red[1]), fmaxf(red[2], red[3]));
}

__device__ __forceinline__ unsigned short f32_to_bf16_rne(float f) {
  unsigned u = __float_as_uint(f);
  unsigned r = (u + 0x7FFFu + ((u >> 16) & 1u)) >> 16;
  return (unsigned short)r;
}
__device__ __forceinline__ float bf16_to_f32(unsigned short h) {
  return __uint_as_float(((unsigned)h) << 16);
}

// swizzled offset into a [64][64] bf16 LDS tile (k multiple of 8 for frag reads)
__device__ __forceinline__ int swz(int row, int k) {
  return row * 64 + ((((k >> 3) ^ (row & 7))) << 3) + (k & 7);
}

// ---------------- layernorm ----------------
__global__ void ln_kernel(const float* __restrict__ x, const float* __restrict__ w,
                          const float* __restrict__ b, float* __restrict__ out) {
  int t = blockIdx.x, tid = threadIdx.x;
  __shared__ float red[4];
  float ls = 0.f;
  for (int c = tid; c < CC; c += 256) ls += x[t * CC + c];
  float mean = block_sum(ls, red) * (1.f / CC);
  float lv = 0.f;
  for (int c = tid; c < CC; c += 256) { float d = x[t * CC + c] - mean; lv += d * d; }
  float var = block_sum(lv, red) * (1.f / CC);
  float rs = rsqrtf(var + 1e-5f);
  for (int c = tid; c < CC; c += 256)
    out[t * CC + c] = (x[t * CC + c] - mean) * rs * w[c] + b[c];
}

// ---------------- split-bf16 MFMA GEMM: C = A(MxK) @ W(KxN) (+bias) (+gelu) ----------------
__global__ __launch_bounds__(256) void gemm_mfma(
    const float* __restrict__ A, const float* __restrict__ W,
    const float* __restrict__ bias, float* __restrict__ C,
    int M, int N, int K, int act) {
  __shared__ unsigned short Ah[64 * 64];
  __shared__ unsigned short Al[64 * 64];
  __shared__ unsigned short Bh[64 * 64];
  __shared__ unsigned short Bl[64 * 64];
  int tid = threadIdx.x;
  int lane = tid & 63, wave = tid >> 6;
  int wr = wave >> 1, wc = wave & 1;
  int lr = lane & 15;
  int ksub = (lane >> 4) * 8;
  int n0 = blockIdx.x * 64, m0 = blockIdx.y * 64;

  f32x4 acc[2][2];
#pragma unroll
  for (int i = 0; i < 2; i++)
#pragma unroll
    for (int j = 0; j < 2; j++) acc[i][j] = (f32x4){0.f, 0.f, 0.f, 0.f};

  int lrow = tid >> 2;
  int lq = tid & 3;

  for (int k0 = 0; k0 < K; k0 += 64) {
    {
      const float* src = A + (size_t)(m0 + lrow) * K + k0 + lq * 16;
#pragma unroll
      for (int f = 0; f < 4; f++) {
        float4 v = *(const float4*)(src + f * 4);
        int kk = lq * 16 + f * 4;
        int g = kk >> 3;
        int off = lrow * 64 + ((g ^ (lrow & 7)) << 3) + (kk & 7);
        unsigned short h0 = f32_to_bf16_rne(v.x), h1 = f32_to_bf16_rne(v.y);
        unsigned short h2 = f32_to_bf16_rne(v.z), h3 = f32_to_bf16_rne(v.w);
        *(ushort4*)&Ah[off] = make_ushort4(h0, h1, h2, h3);
        *(ushort4*)&Al[off] = make_ushort4(
            f32_to_bf16_rne(v.x - bf16_to_f32(h0)), f32_to_bf16_rne(v.y - bf16_to_f32(h1)),
            f32_to_bf16_rne(v.z - bf16_to_f32(h2)), f32_to_bf16_rne(v.w - bf16_to_f32(h3)));
      }
    }
    {
      const float* src = W + (size_t)(k0 + lrow) * N + n0 + lq * 16;
      int g = lrow >> 3, krem = lrow & 7;
#pragma unroll
      for (int f = 0; f < 4; f++) {
        float4 v = *(const float4*)(src + f * 4);
        float vv[4] = {v.x, v.y, v.z, v.w};
#pragma unroll
        for (int e = 0; e < 4; e++) {
          int n = lq * 16 + f * 4 + e;
          int off = n * 64 + ((g ^ (n & 7)) << 3) + krem;
          unsigned short hh = f32_to_bf16_rne(vv[e]);
          Bh[off] = hh;
          Bl[off] = f32_to_bf16_rne(vv[e] - bf16_to_f32(hh));
        }
      }
    }
    __syncthreads();
#pragma unroll
    for (int kb = 0; kb < 2; kb++) {
      int kloc = kb * 32 + ksub;
      int g = kloc >> 3;
      bf16x8 ah[2], al[2], bh[2], bl[2];
#pragma unroll
      for (int i = 0; i < 2; i++) {
        int m = wr * 32 + i * 16 + lr;
        int off = m * 64 + ((g ^ (m & 7)) << 3);
        ah[i] = *(const bf16x8*)&Ah[off];
        al[i] = *(const bf16x8*)&Al[off];
      }
#pragma unroll
      for (int j = 0; j < 2; j++) {
        int n = wc * 32 + j * 16 + lr;
        int off = n * 64 + ((g ^ (n & 7)) << 3);
        bh[j] = *(const bf16x8*)&Bh[off];
        bl[j] = *(const bf16x8*)&Bl[off];
      }
#pragma unroll
      for (int i = 0; i < 2; i++)
#pragma unroll
        for (int j = 0; j < 2; j++) {
          acc[i][j] = __builtin_amdgcn_mfma_f32_16x16x32_bf16(ah[i], bh[j], acc[i][j], 0, 0, 0);
          acc[i][j] = __builtin_amdgcn_mfma_f32_16x16x32_bf16(ah[i], bl[j], acc[i][j], 0, 0, 0);
          acc[i][j] = __builtin_amdgcn_mfma_f32_16x16x32_bf16(al[i], bh[j], acc[i][j], 0, 0, 0);
        }
    }
    __syncthreads();
  }
#pragma unroll
  for (int i = 0; i < 2; i++)
#pragma unroll
    for (int j = 0; j < 2; j++) {
      int col = n0 + wc * 32 + j * 16 + lr;
      float bv = bias ? bias[col] : 0.f;
#pragma unroll
      for (int q = 0; q < 4; q++) {
        int row = m0 + wr * 32 + i * 16 + (lane >> 4) * 4 + q;
        float v = acc[i][j][q] + bv;
        if (act == 1) v = 0.5f * v * (1.f + erff(v * 0.70710678118654752f));
        C[(size_t)row * N + col] = v;
      }
    }
}

// ---------------- causal SDPA ----------------
__global__ void sdpa_kernel(const float* __restrict__ qkv, float* __restrict__ y) {
  int h = blockIdx.x, t = blockIdx.y, tid = threadIdx.x;
  __shared__ float qv[DD];
  __shared__ float sc[TT];
  __shared__ float red[4];
  __shared__ float acc2[4][DD];
  if (tid < DD) qv[tid] = qkv[t * 3 * CC + h * DD + tid];
  __syncthreads();
  float lmax = -INFINITY;
  for (int s = tid; s <= t; s += 256) {
    const float* Kp = qkv + s * 3 * CC + CC + h * DD;
    float d = 0.f;
#pragma unroll
    for (int i = 0; i < DD; i++) d += qv[i] * Kp[i];
    d *= 0.125f;
    sc[s] = d;
    lmax = fmaxf(lmax, d);
  }
  float mx = block_max(lmax, red);
  float lsum = 0.f;
  for (int s = tid; s <= t; s += 256) { float e = expf(sc[s] - mx); sc[s] = e; lsum += e; }
  float sum = block_sum(lsum, red);
  __syncthreads();
  int d = tid & 63, c = tid >> 6;
  float part = 0.f;
  for (int s = c; s <= t; s += 4) part += sc[s] * qkv[s * 3 * CC + 2 * CC + h * DD + d];
  acc2[c][d] = part;
  __syncthreads();
  if (tid < DD) {
    float tot = acc2[0][tid] + acc2[1][tid] + acc2[2][tid] + acc2[3][tid];
    y[t * CC + h * DD + tid] = tot / sum;
  }
}

// ---------------- HOA top-64 via bitonic sort ----------------
__global__ void topk_sort_kernel(const float* __restrict__ qh,
                                 const float* __restrict__ K1, const float* __restrict__ K2,
                                 int* __restrict__ idx1, int* __restrict__ idx2) {
  int h = blockIdx.x, t = blockIdx.y, tid = threadIdx.x;
  const float* Kb = blockIdx.z ? K2 : K1;
  int* idxout = (blockIdx.z ? idx2 : idx1) + (h * TT + t) * KKEEP;
  __shared__ float qv[DD];
  __shared__ unsigned long long keys[TT];
  if (tid < DD) qv[tid] = qh[t * CC + h * DD + tid];
  __syncthreads();
  for (int s = tid; s < TT; s += 256) {
    unsigned sv = 0u;
    if (s <= t) {
      const float* Kp = Kb + s * CC + h * DD;
      float d = 0.f;
#pragma unroll
      for (int i = 0; i < DD; i++) d += qv[i] * Kp[i];
      unsigned u = __float_as_uint(d);
      sv = (u & 0x80000000u) ? ~u : (u | 0x80000000u);
    }
    keys[s] = ((unsigned long long)sv << 32) | (unsigned)(~s);
  }
  for (int k = 2; k <= TT; k <<= 1) {
    for (int j = k >> 1; j > 0; j >>= 1) {
      __syncthreads();
      for (int i = tid; i < TT; i += 256) {
        int ixj = i ^ j;
        if (ixj > i) {
          unsigned long long a = keys[i], b = keys[ixj];
          bool desc = (i & k) == 0;
          if (desc ? (a < b) : (a > b)) { keys[i] = b; keys[ixj] = a; }
        }
      }
    }
  }
  __syncthreads();
  for (int jj = tid; jj < KKEEP; jj += 256) {
    unsigned long long key = keys[jj <= t ? jj : t];
    idxout[jj] = (int)(~(unsigned)key);
  }
}

// ---------------- HOA core: MFMA version (per (h,t) block, 4 waves) ----------------
// A = (q.K1g) @ K2g^T -> in-register row softmax -> inner = alpha @ V2g -> out = colsum(V1g . inner)
__global__ __launch_bounds__(256) void hoa_core_kernel(
    const float* __restrict__ qh,
    const float* __restrict__ K1, const float* __restrict__ K2,
    const float* __restrict__ V1, const float* __restrict__ V2,
    const int* __restrict__ idx1, const int* __restrict__ idx2,
    float* __restrict__ hco) {
  int h = blockIdx.x, t = blockIdx.y, tid = threadIdx.x;
  int lane = tid & 63, w = tid >> 6;
  int lr = lane & 15;
  int ksub = (lane >> 4) * 8;
  const int hDD = h * DD;

  __shared__ unsigned short bufA[64 * 64];  // qk1 -> alpha
  __shared__ unsigned short bufB[64 * 64];  // k2  -> v2t
  __shared__ float v1s[64 * 65];
  __shared__ float red[4 * 64];

  const int* i1 = idx1 + (h * TT + t) * KKEEP;
  const int* i2 = idx2 + (h * TT + t) * KKEEP;

  float qreg = qh[t * CC + hDD + lane];

  // phase 1: gather K1 (pre-multiplied by q), K2, V1
#pragma unroll
  for (int r = 0; r < 16; r++) {
    int j = w * 16 + r;
    int r1 = i1[j], r2 = i2[j];
    float k1v = K1[(size_t)r1 * CC + hDD + lane];
    float k2v = K2[(size_t)r2 * CC + hDD + lane];
    float v1v = V1[(size_t)r1 * CC + hDD + lane];
    int off = swz(j, lane);
    bufA[off] = f32_to_bf16_rne(k1v * qreg);
    bufB[off] = f32_to_bf16_rne(k2v);
    v1s[j * 65 + lane] = v1v;
  }
  __syncthreads();

  // phase 2: A = qk1 @ k2^T  (wave w -> rows [16w,16w+16), all 64 cols)
  f32x4 acc[4];
#pragma unroll
  for (int nt = 0; nt < 4; nt++) acc[nt] = (f32x4){0.f, 0.f, 0.f, 0.f};
  {
    bf16x8 af[2];
#pragma unroll
    for (int kb = 0; kb < 2; kb++)
      af[kb] = *(const bf16x8*)&bufA[swz(w * 16 + lr, kb * 32 + ksub)];
#pragma unroll
    for (int nt = 0; nt < 4; nt++)
#pragma unroll
      for (int kb = 0; kb < 2; kb++) {
        bf16x8 bf = *(const bf16x8*)&bufB[swz(nt * 16 + lr, kb * 32 + ksub)];
        acc[nt] = __builtin_amdgcn_mfma_f32_16x16x32_bf16(af[kb], bf, acc[nt], 0, 0, 0);
      }
  }
  // in-register row softmax (row = 16w + (lane>>4)*4 + q, cols spread over lane&15 and nt)
#pragma unroll
  for (int q = 0; q < 4; q++) {
    float m = -INFINITY;
#pragma unroll
    for (int nt = 0; nt < 4; nt++) {
      acc[nt][q] *= 0.125f;
      m = fmaxf(m, acc[nt][q]);
    }
#pragma unroll
    for (int off = 1; off < 16; off <<= 1) m = fmaxf(m, __shfl_xor(m, off));
    float s = 0.f;
#pragma unroll
    for (int nt = 0; nt < 4; nt++) {
      float e = expf(acc[nt][q] - m);
      acc[nt][q] = e;
      s += e;
    }
#pragma unroll
    for (int off = 1; off < 16; off <<= 1) s += __shfl_xor(s, off);
    float inv = 1.f / s;
#pragma unroll
    for (int nt = 0; nt < 4; nt++) acc[nt][q] *= inv;
  }
  __syncthreads();  // all waves done reading bufA/bufB

  // phase 3: write alpha (bf16) into bufA; gather V2 transposed into bufB
#pragma unroll
  for (int nt = 0; nt < 4; nt++)
#pragma unroll
    for (int q = 0; q < 4; q++) {
      int row = w * 16 + (lane >> 4) * 4 + q;
      int col = nt * 16 + lr;
      bufA[swz(row, col)] = f32_to_bf16_rne(acc[nt][q]);
    }
#pragma unroll
  for (int r = 0; r < 16; r++) {
    int k = w * 16 + r;
    float v2v = V2[(size_t)i2[k] * CC + hDD + lane];  // d = lane
    bufB[swz(lane, k)] = f32_to_bf16_rne(v2v);
  }
  __syncthreads();

  // phase 4: inner = alpha @ v2t^T  (rows j in [16w,16w+16), cols d)
  f32x4 acc2[4];
#pragma unroll
  for (int nt = 0; nt < 4; nt++) acc2[nt] = (f32x4){0.f, 0.f, 0.f, 0.f};
  {
    bf16x8 af[2];
#pragma unroll
    for (int kb = 0; kb < 2; kb++)
      af[kb] = *(const bf16x8*)&bufA[swz(w * 16 + lr, kb * 32 + ksub)];
#pragma unroll
    for (int nt = 0; nt < 4; nt++)
#pragma unroll
      for (int kb = 0; kb < 2; kb++) {
        bf16x8 bf = *(const bf16x8*)&bufB[swz(nt * 16 + lr, kb * 32 + ksub)];
        acc2[nt] = __builtin_amdgcn_mfma_f32_16x16x32_bf16(af[kb], bf, acc2[nt], 0, 0, 0);
      }
  }
  // out[d] = sum_j v1[j][d] * inner[j][d]
#pragma unroll
  for (int nt = 0; nt < 4; nt++) {
    float p = 0.f;
#pragma unroll
    for (int q = 0; q < 4; q++) {
      int row = w * 16 + (lane >> 4) * 4 + q;
      int col = lr + 16 * nt;
      p += acc2[nt][q] * v1s[row * 65 + col];
    }
    p += __shfl_xor(p, 16);
    p += __shfl_xor(p, 32);
    if (lane < 16) red[w * 64 + 16 * nt + lr] = p;
  }
  __syncthreads();
  if (tid < 64) {
    float o = red[tid] + red[64 + tid] + red[128 + tid] + red[192 + tid];
    hco[t * CC + hDD + tid] = o;
  }
}

// ---------------- gate ----------------
__global__ void gate_scores_kernel(const float* __restrict__ hoin,
                                   const float* __restrict__ gw, const float* __restrict__ gb,
                                   float* __restrict__ scores) {
  int t = blockIdx.x, tid = threadIdx.x;
  __shared__ float red[4];
  float part = 0.f;
  for (int c = tid; c < CC; c += 256) part += hoin[t * CC + c] * gw[c];
  float s = block_sum(part, red);
  if (tid == 0) scores[t] = s + gb[0];
}

__global__ void gate_mask_kernel(const float* __restrict__ scores, float* __restrict__ mask) {
  int tid = threadIdx.x;
  __shared__ unsigned long long keys[TT];
  for (int s = tid; s < TT; s += 256) {
    unsigned u = __float_as_uint(scores[s]);
    unsigned sv = (u & 0x80000000u) ? ~u : (u | 0x80000000u);
    keys[s] = ((unsigned long long)sv << 32) | (unsigned)(~s);
    mask[s] = 0.f;
  }
  for (int k = 2; k <= TT; k <<= 1) {
    for (int j = k >> 1; j > 0; j >>= 1) {
      __syncthreads();
      for (int i = tid; i < TT; i += 256) {
        int ixj = i ^ j;
        if (ixj > i) {
          unsigned long long a = keys[i], b = keys[ixj];
          bool desc = (i & k) == 0;
          if (desc ? (a < b) : (a > b)) { keys[i] = b; keys[ixj] = a; }
        }
      }
    }
  }
  __syncthreads();
  for (int jj = tid; jj < TOPG; jj += 256) mask[(int)(~(unsigned)keys[jj])] = 1.f;
}

// ---------------- elementwise ----------------
__global__ void add_kernel(const float* __restrict__ a, const float* __restrict__ b,
                           float* __restrict__ o, int n) {
  int i = blockIdx.x * 256 + threadIdx.x;
  if (i < n) o[i] = a[i] + b[i];
}

__global__ void masked_add_kernel(const float* __restrict__ a, const float* __restrict__ b,
                                  const float* __restrict__ mask, float* __restrict__ o, int n) {
  int i = blockIdx.x * 256 + threadIdx.x;
  if (i < n) o[i] = a[i] + b[i] * mask[i / CC];
}

// ---------------- launcher ----------------
extern "C" void kernel_launch(void* const* d_in, const int* in_sizes, int n_in,
                              void* d_out, int out_size, void* d_ws, size_t ws_size,
                              hipStream_t stream) {
  const float* x      = (const float*)d_in[0];
  const float* ln1_w  = (const float*)d_in[1];
  const float* ln1_b  = (const float*)d_in[2];
  const float* qkv_w  = (const float*)d_in[3];
  const float* qkv_b  = (const float*)d_in[4];
  const float* atto_w = (const float*)d_in[5];
  const float* atto_b = (const float*)d_in[6];
  const float* lnh_w  = (const float*)d_in[7];
  const float* lnh_b  = (const float*)d_in[8];
  const float* hq_w   = (const float*)d_in[9];
  const float* hk1_w  = (const float*)d_in[10];
  const float* hk2_w  = (const float*)d_in[11];
  const float* hv1_w  = (const float*)d_in[12];
  const float* hv2_w  = (const float*)d_in[13];
  const float* ho_w   = (const float*)d_in[14];
  const float* gate_w = (const float*)d_in[15];
  const float* gate_b = (const float*)d_in[16];
  const float* ln2_w  = (const float*)d_in[17];
  const float* ln2_b  = (const float*)d_in[18];
  const float* fc_w   = (const float*)d_in[19];
  const float* fc_b   = (const float*)d_in[20];
  const float* pr_w   = (const float*)d_in[21];
  const float* pr_b   = (const float*)d_in[22];
  float* out = (float*)d_out;

  const size_t NTC = (size_t)TT * CC;
  float* ws   = (float*)d_ws;
  float* h    = ws;
  float* qkv  = h + NTC;
  float* y    = qkv + 3 * NTC;
  float* x1   = y + NTC;
  float* hoin = x1 + NTC;
  float* qh   = hoin + NTC;
  float* K1   = qh + NTC;
  float* K2   = K1 + NTC;
  float* V1   = K2 + NTC;
  float* V2   = V1 + NTC;
  float* hco  = V2 + NTC;
  float* hout = hco + NTC;
  float* x2   = hout + NTC;
  float* h2   = x2 + NTC;
  float* fcb  = h2 + NTC;
  float* scores = fcb + 4 * NTC;
  float* maskb  = scores + TT;
  int* idx1 = (int*)(maskb + TT);
  int* idx2 = idx1 + HH * TT * KKEEP;

  dim3 blk(256);
  int nElem = (int)NTC;
  int nBlocks = (nElem + 255) / 256;

  hipLaunchKernelGGL(ln_kernel, dim3(TT), blk, 0, stream, x, ln1_w, ln1_b, h);
  hipLaunchKernelGGL(gemm_mfma, dim3(3 * CC / 64, TT / 64), blk, 0, stream,
                     h, qkv_w, qkv_b, qkv, TT, 3 * CC, CC, 0);
  hipLaunchKernelGGL(sdpa_kernel, dim3(HH, TT), blk, 0, stream, qkv, y);
  hipLaunchKernelGGL(gemm_mfma, dim3(CC / 64, TT / 64), blk, 0, stream,
                     y, atto_w, atto_b, h, TT, CC, CC, 0);
  hipLaunchKernelGGL(add_kernel, dim3(nBlocks), blk, 0, stream, x, h, x1, nElem);
  hipLaunchKernelGGL(ln_kernel, dim3(TT), blk, 0, stream, x1, lnh_w, lnh_b, hoin);
  hipLaunchKernelGGL(gemm_mfma, dim3(CC / 64, TT / 64), blk, 0, stream,
                     hoin, hq_w, (const float*)nullptr, qh, TT, CC, CC, 0);
  hipLaunchKernelGGL(gemm_mfma, dim3(CC / 64, TT / 64), blk, 0, stream,
                     hoin, hk1_w, (const float*)nullptr, K1, TT, CC, CC, 0);
  hipLaunchKernelGGL(gemm_mfma, dim3(CC / 64, TT / 64), blk, 0, stream,
                     hoin, hk2_w, (const float*)nullptr, K2, TT, CC, CC, 0);
  hipLaunchKernelGGL(gemm_mfma, dim3(CC / 64, TT / 64), blk, 0, stream,
                     hoin, hv1_w, (const float*)nullptr, V1, TT, CC, CC, 0);
  hipLaunchKernelGGL(gemm_mfma, dim3(CC / 64, TT / 64), blk, 0, stream,
                     hoin, hv2_w, (const float*)nullptr, V2, TT, CC, CC, 0);
  hipLaunchKernelGGL(topk_sort_kernel, dim3(HH, TT, 2), blk, 0, stream,
                     qh, K1, K2, idx1, idx2);
  hipLaunchKernelGGL(hoa_core_kernel, dim3(HH, TT), blk, 0, stream,
                     qh, K1, K2, V1, V2, idx1, idx2, hco);
  hipLaunchKernelGGL(gemm_mfma, dim3(CC / 64, TT / 64), blk, 0, stream,
                     hco, ho_w, (const float*)nullptr, hout, TT, CC, CC, 0);
  hipLaunchKernelGGL(gate_scores_kernel, dim3(TT), blk, 0, stream, hoin, gate_w, gate_b, scores);
  hipLaunchKernelGGL(gate_mask_kernel, dim3(1), blk, 0, stream, scores, maskb);
  hipLaunchKernelGGL(masked_add_kernel, dim3(nBlocks), blk, 0, stream, x1, hout, maskb, x2, nElem);
  hipLaunchKernelGGL(ln_kernel, dim3(TT), blk, 0, stream, x2, ln2_w, ln2_b, h2);
  hipLaunchKernelGGL(gemm_mfma, dim3(4 * CC / 64, TT / 64), blk, 0, stream,
                     h2, fc_w, fc_b, fcb, TT, 4 * CC, CC, 1);
  hipLaunchKernelGGL(gemm_mfma, dim3(CC / 64, TT / 64), blk, 0, stream,
                     fcb, pr_w, pr_b, h, TT, CC, 4 * CC, 0);
  hipLaunchKernelGGL(add_kernel, dim3(nBlocks), blk, 0, stream, x2, h, out, nElem);
}